// Round 6
// baseline (214.415 us; speedup 1.0000x reference)
//
#include <hip/hip_runtime.h>
#include <hip/hip_bf16.h>

// ExpertBank MoE FFN on gfx950 — round 15.
// r14 post-mortem: epilogue fix confirmed (66->49.7us). Model across r11-r14: both GEMMs
// stage 268MB of tiles = 2.1M cache lines each; at ~32 lines/cyc chip-wide that's ~27us —
// the dominant term. Remaining lever = reuse: BIGGER TILES.
//   gemm1: 256x256, 8 waves (2x4), acc[8][4], staged 134MB (1.05M lines ~13us), 1 blk/CU,
//          LDS 128KB staging + epilogue C-tile [256][272] reuse (139KB), pvalid 128-granular
//          guard so 256-row tiles never write another expert's padded region.
//   gemm2: 128x256, 8 waves (2x4), acc[4][4], staged 201MB (1.57M lines ~20us), vmcnt=6.
// Same dbuf counted-vmcnt skeleton, slot64 swizzle, pre-swizzled-global DMA (m173).
// ws: int[0..7] counts, [16..23] opad, [32..) rowmap(9216),
//     byte 65536: H bf16 [9216][2048] (37.75 MB), Xb bf16 (4.2 MB),
//     W1T bf16 (16.8 MB), [optional] W2T bf16 (16.8 MB).

typedef __bf16 bf16x8 __attribute__((ext_vector_type(8)));
typedef float f32x4 __attribute__((ext_vector_type(4)));

#define DM 512
#define DF 2048
#define NE 8
#define NTOK 4096
#define NPAIR 8192
#define HCAP 9216

__device__ __forceinline__ unsigned short f2bf(float x) {
    unsigned u = __builtin_bit_cast(unsigned, x);
    return (unsigned short)((u + 0x7fffu + ((u >> 16) & 1u)) >> 16);
}
__device__ __forceinline__ unsigned pack2(float lo, float hi) {
    return (unsigned)f2bf(lo) | ((unsigned)f2bf(hi) << 16);
}
// tanh-form GELU == x*sigmoid(2y); log2e folded: gelu = x * rcp(1 + exp2(z)). |err|~3e-4.
__device__ __forceinline__ float gelu_fast(float x) {
    float x2 = x * x;
    float z = x * __builtin_fmaf(x2, -0.1029432f, -2.3022083f);
    float e = __builtin_amdgcn_exp2f(z);
    return x * __builtin_amdgcn_rcpf(1.0f + e);
}
// async 16B global->LDS (gfx950); lds pointer must be wave-uniform, writes lane*16B
__device__ __forceinline__ void dma16(const unsigned short* g, unsigned short* l) {
    __builtin_amdgcn_global_load_lds(
        (const __attribute__((address_space(1))) void*)g,
        (__attribute__((address_space(3))) void*)l, 16, 0, 0);
}
// BK=64 tile [rows][64] bf16: 8 16B-chunks per 128B row; XOR swizzle chunk^(row&7).
__device__ __forceinline__ int slot64(int row, int c) { return row * 8 + (c ^ (row & 7)); }

// one BMxBNx64 MFMA step (2 x K=32 sub-steps) from swizzled LDS tiles; FM row-frags, 4 col-frags
template<int FM>
__device__ __forceinline__ void mfma_tileT(const unsigned short* Ab, const unsigned short* Bb,
                                           int rbase, int cbase, int quad, int l15,
                                           f32x4 (&acc)[FM][4]) {
#pragma unroll
    for (int kk = 0; kk < 2; ++kk) {
        const int c = kk * 4 + quad;
        bf16x8 a[FM], b[4];
#pragma unroll
        for (int fm = 0; fm < FM; ++fm)
            a[fm] = __builtin_bit_cast(bf16x8, *(const uint4*)&Ab[slot64(rbase + fm * 16 + l15, c) * 8]);
#pragma unroll
        for (int fn = 0; fn < 4; ++fn)
            b[fn] = __builtin_bit_cast(bf16x8, *(const uint4*)&Bb[slot64(cbase + fn * 16 + l15, c) * 8]);
#pragma unroll
        for (int fm = 0; fm < FM; ++fm)
#pragma unroll
            for (int fn = 0; fn < 4; ++fn)
                acc[fm][fn] = __builtin_amdgcn_mfma_f32_16x16x32_bf16(a[fm], b[fn], acc[fm][fn], 0, 0, 0);
    }
}

#define WAITN(n)                                                  \
    do {                                                          \
        __builtin_amdgcn_sched_barrier(0);                        \
        asm volatile("s_waitcnt vmcnt(" #n ")" ::: "memory");     \
        __builtin_amdgcn_sched_barrier(0);                        \
    } while (0)

#define BAR() __builtin_amdgcn_s_barrier()

// ---- mega-prep: [0,1024) cvtX, [1024,3072) tw(W1), 3072 routing,
// ----            [3073,5121) tw(W2)  (only dispatched in fused mode) ----
__global__ void k_prep(const float* __restrict__ X, unsigned short* __restrict__ Xb,
                       const float* __restrict__ W1, unsigned short* __restrict__ W1T,
                       const float* __restrict__ W2, unsigned short* __restrict__ W2T,
                       const int* __restrict__ sel, int* __restrict__ counts_g,
                       int* __restrict__ opad_g, int* __restrict__ rowmap,
                       float* __restrict__ loads_out) {
    __shared__ unsigned short T[64][65];
    __shared__ int hist[NE], cur[NE], off[NE];
    const int b = blockIdx.x, tid = threadIdx.x;

    if (b < 1024) {  // X fp32 -> bf16
        int i = (b * 256 + tid) * 8;
        float4 a = *(const float4*)(X + i);
        float4 c = *(const float4*)(X + i + 4);
        uint4 u;
        u.x = pack2(a.x, a.y); u.y = pack2(a.z, a.w);
        u.z = pack2(c.x, c.y); u.w = pack2(c.z, c.w);
        *(uint4*)(Xb + i) = u;
    } else if (b < 3072) {  // W1 [E][DM][DF] -> bf16 W1T [E][DF][DM]
        const int t = b - 1024;
        const int bx = t & 31, by = (t >> 5) & 7, bz = t >> 8;
        const int tx = tid & 15, ty = tid >> 4;
        const int r0 = by * 64, c0 = bx * 64;
        const float* src = W1 + ((size_t)bz * DM + r0) * DF + c0;
#pragma unroll
        for (int i = 0; i < 4; ++i) {
            int r = ty + i * 16;
            float4 v = *(const float4*)(src + (size_t)r * DF + tx * 4);
            T[tx * 4 + 0][r] = f2bf(v.x); T[tx * 4 + 1][r] = f2bf(v.y);
            T[tx * 4 + 2][r] = f2bf(v.z); T[tx * 4 + 3][r] = f2bf(v.w);
        }
        __syncthreads();
        unsigned short* dst = W1T + ((size_t)bz * DF + c0) * DM + r0;
#pragma unroll
        for (int i = 0; i < 4; ++i) {
            int c = ty + i * 16;
            ushort4 w;
            w.x = T[c][tx * 4 + 0]; w.y = T[c][tx * 4 + 1];
            w.z = T[c][tx * 4 + 2]; w.w = T[c][tx * 4 + 3];
            *(ushort4*)(dst + (size_t)c * DM + tx * 4) = w;
        }
    } else if (b == 3072) {  // routing: histogram + padded scan + compact assign
        if (tid < NE) { hist[tid] = 0; cur[tid] = 0; }
        __syncthreads();
#pragma unroll
        for (int i = 0; i < NPAIR / 256; ++i)
            atomicAdd(&hist[sel[i * 256 + tid]], 1);
        __syncthreads();
        if (tid == 0) {
            int s = 0;
            for (int e = 0; e < NE; ++e) {
                off[e] = s;
                s += (hist[e] + 127) & ~127;
                counts_g[e] = hist[e];
                opad_g[e] = off[e];
                loads_out[e] = (float)hist[e] * (1.0f / (float)NTOK);
            }
        }
        __syncthreads();
#pragma unroll
        for (int i = 0; i < NPAIR / 256; ++i) {
            int p = i * 256 + tid;
            int e = sel[p];
            int pos = atomicAdd(&cur[e], 1);
            rowmap[off[e] + pos] = p;
        }
    } else {  // W2 [E][DF][DM] -> bf16 W2T [E][DM][DF] (fused mode only)
        const int t = b - 3073;
        const int bx = t & 7, by = (t >> 3) & 31, bz = t >> 8;
        const int tx = tid & 15, ty = tid >> 4;
        const int r0 = by * 64, c0 = bx * 64;
        const float* src = W2 + ((size_t)bz * DF + r0) * DM + c0;
#pragma unroll
        for (int i = 0; i < 4; ++i) {
            int r = ty + i * 16;
            float4 v = *(const float4*)(src + (size_t)r * DM + tx * 4);
            T[tx * 4 + 0][r] = f2bf(v.x); T[tx * 4 + 1][r] = f2bf(v.y);
            T[tx * 4 + 2][r] = f2bf(v.z); T[tx * 4 + 3][r] = f2bf(v.w);
        }
        __syncthreads();
        unsigned short* dst = W2T + ((size_t)bz * DM + c0) * DF + r0;
#pragma unroll
        for (int i = 0; i < 4; ++i) {
            int c = ty + i * 16;
            ushort4 w;
            w.x = T[c][tx * 4 + 0]; w.y = T[c][tx * 4 + 1];
            w.z = T[c][tx * 4 + 2]; w.w = T[c][tx * 4 + 3];
            *(ushort4*)(dst + (size_t)c * DF + tx * 4) = w;
        }
    }
}

// ---- W2 [E][DF][DM] -> bf16 W2T [E][DM][DF] (fallback when ws too small to fuse) ----
__global__ void k_tw2(const float* __restrict__ in, unsigned short* __restrict__ out) {
    __shared__ unsigned short T[64][65];
    const int tid = threadIdx.x;
    const int tx = tid & 15, ty = tid >> 4;
    const int r0 = blockIdx.y * 64, c0 = blockIdx.x * 64;
    const float* src = in + ((size_t)blockIdx.z * DF + r0) * DM + c0;
#pragma unroll
    for (int i = 0; i < 4; ++i) {
        int r = ty + i * 16;
        float4 v = *(const float4*)(src + (size_t)r * DM + tx * 4);
        T[tx * 4 + 0][r] = f2bf(v.x); T[tx * 4 + 1][r] = f2bf(v.y);
        T[tx * 4 + 2][r] = f2bf(v.z); T[tx * 4 + 3][r] = f2bf(v.w);
    }
    __syncthreads();
    unsigned short* dst = out + ((size_t)blockIdx.z * DM + c0) * DF + r0;
#pragma unroll
    for (int i = 0; i < 4; ++i) {
        int c = ty + i * 16;
        ushort4 w;
        w.x = T[c][tx * 4 + 0]; w.y = T[c][tx * 4 + 1];
        w.z = T[c][tx * 4 + 2]; w.w = T[c][tx * 4 + 3];
        *(ushort4*)(dst + (size_t)c * DF + tx * 4) = w;
    }
}

// ------ GEMM1: H = gelu(Xb[tok] @ W1), 256x256, 8 waves, BK=64, dbuf counted-vmcnt ------
// LDS: staging A/B dbuf 128KB; epilogue reuses region as [256][272] bf16 C-tile (139KB).
#define STAGE1(buf, ko)                                        \
    do {                                                       \
        _Pragma("unroll") for (int j_ = 0; j_ < 4; ++j_) {     \
            dma16(ga[j_] + (ko), la[j_] + (buf) * 16384);      \
            dma16(gb[j_] + (ko), lb[j_] + (buf) * 16384);      \
        }                                                      \
    } while (0)

__launch_bounds__(512, 2)
__global__ void k_gemm1d(const unsigned short* __restrict__ Xb,
                         const unsigned short* __restrict__ W1T,
                         const int* __restrict__ counts, const int* __restrict__ opad,
                         const int* __restrict__ rowmap, unsigned short* __restrict__ H) {
    const int e = blockIdx.z, mt = blockIdx.y, nt = blockIdx.x;
    const int grow = opad[e] + mt * 256;
    int valid = counts[e] - mt * 256;
    if (valid <= 0) return;
    if (valid > 256) valid = 256;

    __shared__ __align__(16) unsigned char SMRAW[256 * 272 * 2];  // 139264 B
    __shared__ int toks[256];
    unsigned short* As = (unsigned short*)SMRAW;   // [2][16384] ushorts
    unsigned short* Bs = As + 32768;               // [2][16384] ushorts

    const int tid = threadIdx.x;
    if (tid < 256) {
        int i = (tid < valid) ? tid : 0;
        toks[tid] = rowmap[grow + i] >> 1;
    }
    __syncthreads();

    const int wave = tid >> 6, lane = tid & 63;
    const int quad = lane >> 4, l15 = lane & 15;
    const int rbase = (wave >> 2) * 128, cbase = (wave & 3) * 64;

    // DMA: 2048 slots per operand; wave covers slots [wave*256, wave*256+256)
    const unsigned short* ga[4];
    const unsigned short* gb[4];
    unsigned short* la[4];
    unsigned short* lb[4];
#pragma unroll
    for (int j = 0; j < 4; ++j) {
        int slot = wave * 256 + j * 64 + lane;
        int row = slot >> 3;
        int ch = (slot & 7) ^ (row & 7);  // pre-swizzled global source (m173)
        ga[j] = Xb + (size_t)toks[row] * DM + ch * 8;
        gb[j] = W1T + ((size_t)e * DF + nt * 256 + row) * DM + ch * 8;
        la[j] = As + (wave * 256 + j * 64) * 8;
        lb[j] = Bs + (wave * 256 + j * 64) * 8;
    }

    f32x4 acc[8][4] = {};

    STAGE1(0, 0);
#pragma unroll 1
    for (int kt = 0; kt < 8; kt += 2) {
        if (kt + 1 < 8) { STAGE1(1, (kt + 1) * 64); WAITN(8); } else { WAITN(0); }
        BAR();
        mfma_tileT<8>(As, Bs, rbase, cbase, quad, l15, acc);
        BAR();
        if (kt + 2 < 8) { STAGE1(0, (kt + 2) * 64); WAITN(8); } else { WAITN(0); }
        BAR();
        mfma_tileT<8>(As + 16384, Bs + 16384, rbase, cbase, quad, l15, acc);
        BAR();
    }

    // ---- epilogue: gelu+cvt into LDS C-tile [256][272], then coalesced 16B stores ----
    unsigned short* ep = (unsigned short*)SMRAW;
#pragma unroll
    for (int fm = 0; fm < 8; ++fm)
#pragma unroll
        for (int i = 0; i < 4; ++i) {
            int r = rbase + fm * 16 + quad * 4 + i;
#pragma unroll
            for (int fn = 0; fn < 4; ++fn)
                ep[r * 272 + cbase + fn * 16 + l15] = f2bf(gelu_fast(acc[fm][fn][i]));
        }
    __syncthreads();
    {
        const int pvalid = (valid + 127) & ~127;  // never cross into next expert's region
        const int ch = tid & 31, rr = tid >> 5;
#pragma unroll
        for (int it = 0; it < 16; ++it) {
            int r = it * 16 + rr;
            if (r < pvalid) {
                uint4 v = *(const uint4*)&ep[r * 272 + ch * 8];
                *(uint4*)(H + (size_t)(grow + r) * DF + nt * 256 + ch * 8) = v;
            }
        }
    }
}

// ------ GEMM2: out = H @ W2 (K=2048, plain stores), 128x256, 8 waves, dbuf vmcnt(6) ------
#define STAGE2(buf, ko)                                        \
    do {                                                       \
        _Pragma("unroll") for (int j_ = 0; j_ < 2; ++j_)       \
            dma16(ga[j_] + (ko), la[j_] + (buf) * 8192);       \
        _Pragma("unroll") for (int j_ = 0; j_ < 4; ++j_)       \
            dma16(gb[j_] + (ko), lb[j_] + (buf) * 16384);      \
    } while (0)

__launch_bounds__(512, 2)
__global__ void k_gemm2d(const unsigned short* __restrict__ H,
                         const unsigned short* __restrict__ W2T,
                         const int* __restrict__ counts, const int* __restrict__ opad,
                         const int* __restrict__ rowmap, float* __restrict__ out) {
    const int e = blockIdx.z, mt = blockIdx.y, nt = blockIdx.x;
    const int grow = opad[e] + mt * 128;
    int valid = counts[e] - mt * 128;
    if (valid <= 0) return;
    if (valid > 128) valid = 128;

    __shared__ __align__(16) unsigned short As2[2][8192];    // 32 KB  (A: 128x64)
    __shared__ __align__(16) unsigned short Bs2[2][16384];   // 64 KB  (B: 256x64)
    __shared__ int pairs[128];

    const int tid = threadIdx.x;
    if (tid < 128) pairs[tid] = (tid < valid) ? rowmap[grow + tid] : 0;
    __syncthreads();

    const int wave = tid >> 6, lane = tid & 63;
    const int quad = lane >> 4, l15 = lane & 15;
    const int rbase = (wave >> 2) * 64, cbase = (wave & 3) * 64;

    const unsigned short* ga[2];
    unsigned short* la[2];
#pragma unroll
    for (int j = 0; j < 2; ++j) {
        int slot = wave * 128 + j * 64 + lane;
        int row = slot >> 3;
        int ch = (slot & 7) ^ (row & 7);
        int rr = (row < valid) ? row : 0;  // clamp: never read unwritten H (r7 lesson)
        ga[j] = H + (size_t)(grow + rr) * DF + ch * 8;
        la[j] = &As2[0][(wave * 128 + j * 64) * 8];
    }
    const unsigned short* gb[4];
    unsigned short* lb[4];
#pragma unroll
    for (int j = 0; j < 4; ++j) {
        int slot = wave * 256 + j * 64 + lane;
        int row = slot >> 3;
        int ch = (slot & 7) ^ (row & 7);
        gb[j] = W2T + ((size_t)e * DM + nt * 256 + row) * DF + ch * 8;
        lb[j] = &Bs2[0][(wave * 256 + j * 64) * 8];
    }

    f32x4 acc[4][4] = {};

    STAGE2(0, 0);
#pragma unroll 1
    for (int kt = 0; kt < 32; kt += 2) {
        if (kt + 1 < 32) { STAGE2(1, (kt + 1) * 64); WAITN(6); } else { WAITN(0); }
        BAR();
        mfma_tileT<4>(&As2[0][0], &Bs2[0][0], rbase, cbase, quad, l15, acc);
        BAR();
        if (kt + 2 < 32) { STAGE2(0, (kt + 2) * 64); WAITN(6); } else { WAITN(0); }
        BAR();
        mfma_tileT<4>(&As2[1][0], &Bs2[1][0], rbase, cbase, quad, l15, acc);
        BAR();
    }

#pragma unroll
    for (int fm = 0; fm < 4; ++fm) {
#pragma unroll
        for (int i = 0; i < 4; ++i) {
            int m_l = rbase + fm * 16 + quad * 4 + i;
            if (m_l < valid) {
                float* orow = out + (size_t)pairs[m_l] * DM + nt * 256 + cbase;
#pragma unroll
                for (int fn = 0; fn < 4; ++fn)
                    orow[fn * 16 + l15] = acc[fm][fn][i];  // exactly-once: plain store
            }
        }
    }
}

extern "C" void kernel_launch(void* const* d_in, const int* in_sizes, int n_in,
                              void* d_out, int out_size, void* d_ws, size_t ws_size,
                              hipStream_t stream) {
    const float* X = (const float*)d_in[0];
    const int* sel = (const int*)d_in[1];
    const float* W1 = (const float*)d_in[3];
    const float* W2 = (const float*)d_in[4];
    float* out = (float*)d_out;
    float* loads_out = out + (size_t)NPAIR * DM;

    int* counts = (int*)d_ws;
    int* opad = counts + 16;
    int* rowmap = counts + 32;
    const size_t hbytes = (size_t)HCAP * DF * 2;
    const size_t xbytes = (size_t)NTOK * DM * 2;
    const size_t w1tbytes = (size_t)NE * DF * DM * 2;
    unsigned short* H = (unsigned short*)((char*)d_ws + 65536);
    unsigned short* Xb = (unsigned short*)((char*)d_ws + 65536 + hbytes);
    unsigned short* WT = (unsigned short*)((char*)d_ws + 65536 + hbytes + xbytes);

    // fused mode: separate W2T buffer -> W2 transpose folds into k_prep, no k_tw2 dispatch
    const bool fused = ws_size >= 65536 + hbytes + xbytes + 2 * w1tbytes;
    unsigned short* W2T = fused ? WT + w1tbytes / 2 : WT;

    hipLaunchKernelGGL(k_prep, dim3(fused ? 5121 : 3073), dim3(256), 0, stream,
                       X, Xb, W1, WT, W2, W2T, sel, counts, opad, rowmap, loads_out);
    hipLaunchKernelGGL(k_gemm1d, dim3(DF / 256, NPAIR / 256, NE), dim3(512), 0, stream,
                       Xb, WT, counts, opad, rowmap, H);
    if (!fused)
        hipLaunchKernelGGL(k_tw2, dim3(DM / 64, DF / 64, NE), dim3(256), 0, stream, W2, WT);
    hipLaunchKernelGGL(k_gemm2d, dim3(DM / 256, NPAIR / 128, NE), dim3(512), 0, stream,
                       H, W2T, counts, opad, rowmap, out);
}